// Round 3
// baseline (98419.061 us; speedup 1.0000x reference)
//
#include <hip/hip_runtime.h>

// ---------------------------------------------------------------------------
// Bidirectional stacked GRU decoder. B=64, S=512, I=H=512, L=2.
// Round-3: on-device dtype detection (f32 vs bf16 device buffers), dual-path
// loads/stores (layer offsets resolved device-side in elements), ws_size-
// adaptive chunking. Internal: gi f32, h f32 master + bf16 MFMA copies,
// out1c bf16.
// ---------------------------------------------------------------------------

#define B_    64
#define S_    512
#define H_    512
#define G3_   1536

typedef __attribute__((ext_vector_type(8))) __bf16 bf16x8;
typedef __attribute__((ext_vector_type(8))) short short8;
typedef __attribute__((ext_vector_type(4))) float f32x4;

__device__ __forceinline__ float b2f(unsigned short u) {
  union { unsigned int i; float f; } v; v.i = ((unsigned int)u) << 16; return v.f;
}
__device__ __forceinline__ unsigned short f2b(float f) {
  union { float f; unsigned int i; } v; v.f = f;
  unsigned int x = v.i;
  return (unsigned short)((x + 0x7fffu + ((x >> 16) & 1u)) >> 16);
}
__device__ __forceinline__ bf16x8 load8(const unsigned short* p) {
  short8 s = *(const short8*)p;
  return __builtin_bit_cast(bf16x8, s);
}
// 8 consecutive elements at element-index i, either dtype, as bf16x8.
__device__ __forceinline__ bf16x8 load8m(const void* p, size_t i, bool bf) {
  if (bf) return load8((const unsigned short*)p + i);
  const float* f = (const float*)p + i;
  short8 s;
#pragma unroll
  for (int j = 0; j < 8; ++j) s[j] = (short)f2b(f[j]);
  return __builtin_bit_cast(bf16x8, s);
}
__device__ __forceinline__ float loadf(const void* p, size_t i, bool bf) {
  return bf ? b2f(((const unsigned short*)p)[i]) : ((const float*)p)[i];
}
__device__ __forceinline__ f32x4 mfma16(bf16x8 a, bf16x8 b, f32x4 c) {
  return __builtin_amdgcn_mfma_f32_16x16x32_bf16(a, b, c, 0, 0, 0);
}
// Overflow-proof: exp() only ever sees non-positive arguments.
__device__ __forceinline__ float sigmoidf_(float x) {
  float e = __expf(-fabsf(x));
  float s = e / (1.0f + e);
  return x >= 0.0f ? 1.0f - s : s;
}
__device__ __forceinline__ float tanhf_(float x) {
  float e = __expf(-2.0f * fabsf(x));
  float r = (1.0f - e) / (1.0f + e);
  return x >= 0.0f ? r : -r;
}

// ---------------------------------------------------------------------------
// dtype detect: low 16 bits of 32-bit words of x are valid-exponent bf16s
// only if the buffer is packed bf16; in f32 data they're uniform mantissa bits.
// ---------------------------------------------------------------------------
__global__ void detect_mode(const unsigned int* __restrict__ x, int* __restrict__ flag) {
  int lane = threadIdx.x;                      // 64 threads, 1 block
  unsigned int w = x[(size_t)lane * 997];      // max word idx 62811 << 8.39M (bf16 bound)
  unsigned int lo = w & 0xFFFFu;
  int e = (int)((lo >> 7) & 0xFF);
  int hit = (e >= 100 && e <= 140) ? 1 : 0;
  unsigned long long m = __ballot(hit);
  if (lane == 0) flag[0] = (__popcll(m) >= 48) ? 1 : 0;   // 1 = bf16 buffers
}

// ---------------------------------------------------------------------------
// init hidden states. NOTE reference quirk: every layer's scan starts from h0
// (encoder slice), not the previous layer's h_last.
// hstate layout: [layer(2)][dir(2)][b(64)][H] fp32
// ---------------------------------------------------------------------------
__global__ void init_state(const void* __restrict__ enc,
                           float* __restrict__ hstate,
                           const int* __restrict__ mode) {
  const bool bf = mode[0] != 0;
  int i = blockIdx.x * 256 + threadIdx.x;      // 0 .. 64*1024-1
  if (i >= B_ * 2 * H_) return;
  int b = i >> 10, j = i & 1023;
  int d = j >> 9, c = j & 511;
  float v = loadf(enc, i, bf);
  hstate[(((size_t)0 * 2 + d) * B_ + b) * H_ + c] = v;
  hstate[(((size_t)1 * 2 + d) * B_ + b) * H_ + c] = v;
}

// ---------------------------------------------------------------------------
// gi GEMM: gi[m][g] = A[m].Wih[g] + bih[g] (f32 out), m enumerates (d,n,b).
// Grid (24, 2*CH), block 256 (4 waves); wave = 16x64 C-strip.
// Layer weight offset applied device-side in ELEMENTS (dtype-agnostic).
// ---------------------------------------------------------------------------
__global__ __launch_bounds__(256) void gi_gemm(
    const void* __restrict__ xin,              // layer0: x (mode dtype); layer1: out1c (bf16)
    const void* __restrict__ WihF, const void* __restrict__ WihB,
    const void* __restrict__ bihF, const void* __restrict__ bihB,
    float* __restrict__ gi,                    // [2*CH*64][G3] f32
    const int* __restrict__ mode,
    int chunk, int layer, int CH) {
  const bool bf = mode[0] != 0;
  const bool abf = (layer == 1) ? true : bf;   // out1c is always bf16
  const size_t WOFF = (size_t)layer * G3_ * H_;  // element offset of this layer's Wih
  const size_t BOFF = (size_t)layer * G3_;
  const int lane = threadIdx.x & 63;
  const int wave = threadIdx.x >> 6;           // 0..3
  const int tn = blockIdx.x;                   // 0..23
  const int tm = blockIdx.y;                   // 0..2*CH-1
  const int d = (tm >= CH) ? 1 : 0;
  const int tmd = tm - d * CH;                 // within-dir time index
  const int rowA = lane & 15;
  const int kb = lane >> 4;                    // 0..3

  size_t abase;
  if (layer == 0) {
    int b = wave * 16 + rowA;
    int tt = chunk * CH + tmd;
    int t = d ? (S_ - 1 - tt) : tt;
    abase = ((size_t)b * S_ + t) * H_;
  } else {
    int m = tm * 64 + wave * 16 + rowA;
    abase = (size_t)m * H_;
  }
  const void* W = d ? WihB : WihF;
  const void* bih = d ? bihB : bihF;

  f32x4 acc[4] = {{0,0,0,0},{0,0,0,0},{0,0,0,0},{0,0,0,0}};
  size_t wrow[4];
#pragma unroll
  for (int nt = 0; nt < 4; ++nt)
    wrow[nt] = WOFF + (size_t)(tn * 64 + nt * 16 + rowA) * H_ + kb * 8;
  const size_t ab = abase + kb * 8;

#pragma unroll 4
  for (int kk = 0; kk < 16; ++kk) {
    bf16x8 a = load8m(xin, ab + kk * 32, abf);
#pragma unroll
    for (int nt = 0; nt < 4; ++nt) {
      bf16x8 b = load8m(W, wrow[nt] + kk * 32, bf);
      acc[nt] = mfma16(a, b, acc[nt]);
    }
  }

#pragma unroll
  for (int nt = 0; nt < 4; ++nt) {
    int g = tn * 64 + nt * 16 + rowA;          // C col = lane&15
    float bb = loadf(bih, BOFF + g, bf);
#pragma unroll
    for (int rg = 0; rg < 4; ++rg) {
      int mrow = tm * 64 + wave * 16 + kb * 4 + rg;  // C row = (lane>>4)*4+reg
      gi[(size_t)mrow * G3_ + g] = acc[nt][rg] + bb;
    }
  }
}

// ---------------------------------------------------------------------------
// Recurrence: grid 8 = dir(2) x chain-group(4); block 512 (8 waves); CH steps.
// ---------------------------------------------------------------------------
__global__ __launch_bounds__(512) void rec_kernel(
    const float* __restrict__ gi,              // [2*CH*64][G3] f32
    const void* __restrict__ WhhF, const void* __restrict__ WhhB,
    const void* __restrict__ bhhF, const void* __restrict__ bhhB,
    float* __restrict__ hstate,                // this layer: [2][B][H]
    unsigned short* __restrict__ out1c,        // layer0 dest (bf16)
    void* __restrict__ dout,                   // layer1 dest (mode dtype)
    const int* __restrict__ mode,
    int chunk, int layer, int CH) {
  __shared__ float hf[16][516];
  __shared__ unsigned short hbuf[16][520];

  const bool bf = mode[0] != 0;
  const size_t WOFF = (size_t)layer * G3_ * H_;
  const size_t BOFF = (size_t)layer * G3_;
  const int tid = threadIdx.x;
  const int lane = tid & 63;
  const int wave = tid >> 6;                   // 0..7
  const int d = (int)blockIdx.x >> 2;
  const int grp = (int)blockIdx.x & 3;
  const int bbase = grp * 16;
  const void* Whh = d ? WhhB : WhhF;
  const void* bhh = d ? bhhB : bhhF;
  float* hst = hstate + ((size_t)d * B_ + bbase) * H_;

  for (int i = tid; i < 16 * H_; i += 512) {
    int r = i >> 9, c = i & 511;
    float v = hst[r * H_ + c];
    hf[r][c] = v;
    hbuf[r][c] = f2b(v);
  }
  __syncthreads();

  const int rowA = lane & 15;
  const int kb = lane >> 4;                    // 0..3

  for (int n = 0; n < CH; ++n) {
    bf16x8 afr[16];
#pragma unroll
    for (int kk = 0; kk < 16; ++kk)
      afr[kk] = load8(&hbuf[rowA][kk * 32 + kb * 8]);
    __syncthreads();   // A-frag reads complete before h is overwritten

    const size_t gibase = (size_t)((d * CH + n) * 64) * G3_;

#pragma unroll 1
    for (int qi = 0; qi < 4; ++qi) {
      const int q = wave * 4 + qi;             // 0..31: h-col tile
      const int hc = q * 16 + rowA;
      f32x4 ar = {0,0,0,0}, az = {0,0,0,0}, an = {0,0,0,0};
      const size_t wr = WOFF + (size_t)(q * 16 + rowA) * H_ + kb * 8;
#pragma unroll
      for (int kk = 0; kk < 16; ++kk) {
        bf16x8 br = load8m(Whh, wr + kk * 32, bf);
        bf16x8 bz = load8m(Whh, wr + 262144 + kk * 32, bf);
        bf16x8 bn = load8m(Whh, wr + 524288 + kk * 32, bf);
        ar = mfma16(afr[kk], br, ar);
        az = mfma16(afr[kk], bz, az);
        an = mfma16(afr[kk], bn, an);
      }
      const float bhr = loadf(bhh, BOFF + hc, bf);
      const float bhz = loadf(bhh, BOFF + 512 + hc, bf);
      const float bhn = loadf(bhh, BOFF + 1024 + hc, bf);
#pragma unroll
      for (int rg = 0; rg < 4; ++rg) {
        const int rl = kb * 4 + rg;            // chain-local row (C layout)
        const int b = bbase + rl;
        const float* gip = gi + gibase + (size_t)b * G3_;
        float rgate = sigmoidf_(gip[hc] + ar[rg] + bhr);
        float zgate = sigmoidf_(gip[512 + hc] + az[rg] + bhz);
        float nval = tanhf_(gip[1024 + hc] + rgate * (an[rg] + bhn));
        float hnew = (1.0f - zgate) * nval + zgate * hf[rl][hc];
        hf[rl][hc] = hnew;
        unsigned short hb16 = f2b(hnew);
        hbuf[rl][hc] = hb16;
        if (layer == 0) {
          out1c[(size_t)((d * CH + n) * 64 + b) * H_ + hc] = hb16;
        } else {
          int tt = chunk * CH + n;
          int t = d ? (S_ - 1 - tt) : tt;
          size_t oi = ((size_t)b * S_ + t) * (2 * H_) + (size_t)d * H_ + hc;
          if (bf) ((unsigned short*)dout)[oi] = hb16;
          else    ((float*)dout)[oi] = hnew;
        }
      }
    }
    __syncthreads();   // h fully updated before next step's A-frag reads
  }

  for (int i = tid; i < 16 * H_; i += 512) {
    int r = i >> 9, c = i & 511;
    hst[r * H_ + c] = hf[r][c];
  }
}

// ---------------------------------------------------------------------------
// Final hidden epilogue: h_f = out[:, S-1, :H], h_b = out[:, 0, H:2H]
// ---------------------------------------------------------------------------
__global__ void h_epi(void* __restrict__ dout, const int* __restrict__ mode) {
  const bool bf = mode[0] != 0;
  int i = blockIdx.x * 256 + threadIdx.x;      // 0 .. 64*1024-1
  if (i >= B_ * 2 * H_) return;
  int b = i >> 10, j = i & 1023;
  int t = (j < H_) ? (S_ - 1) : 0;
  size_t src = ((size_t)b * S_ + t) * (2 * H_) + j;
  size_t dst = (size_t)B_ * S_ * 2 * H_ + i;
  if (bf) ((unsigned short*)dout)[dst] = ((const unsigned short*)dout)[src];
  else    ((float*)dout)[dst] = ((const float*)dout)[src];
}

// ---------------------------------------------------------------------------
extern "C" void kernel_launch(void* const* d_in, const int* in_sizes, int n_in,
                              void* d_out, int out_size, void* d_ws, size_t ws_size,
                              hipStream_t stream) {
  const void* x    = d_in[0];
  const void* enc  = d_in[1];
  const void* WihF = d_in[2];
  const void* WhhF = d_in[3];
  const void* bihF = d_in[4];
  const void* bhhF = d_in[5];
  const void* WihB = d_in[6];
  const void* WhhB = d_in[7];
  const void* bihB = d_in[8];
  const void* bhhB = d_in[9];

  // ws layout: [flag 512B][hstate 512KB][out1c CH*128KB bf16][gi CH*768KB f32]
  int CH = 16;
  while (CH > 1 && (size_t)512 + 524288 + (size_t)CH * (131072 + 786432) > ws_size)
    CH >>= 1;
  char* ws = (char*)d_ws;
  int* flag             = (int*)ws;
  float* hstate         = (float*)(ws + 512);
  unsigned short* out1c = (unsigned short*)(ws + 512 + 524288);
  float* gi             = (float*)(ws + 512 + 524288 + (size_t)CH * 131072);
  const int NCH = S_ / CH;

  detect_mode<<<1, 64, 0, stream>>>((const unsigned int*)x, flag);
  init_state<<<256, 256, 0, stream>>>(enc, hstate, flag);

  for (int c = 0; c < NCH; ++c) {
    // ----- layer 0 -----
    gi_gemm<<<dim3(24, 2 * CH), 256, 0, stream>>>(
        x, WihF, WihB, bihF, bihB, gi, flag, c, 0, CH);
    rec_kernel<<<8, 512, 0, stream>>>(
        gi, WhhF, WhhB, bhhF, bhhB, hstate, out1c, nullptr, flag, c, 0, CH);
    // ----- layer 1 -----
    gi_gemm<<<dim3(24, 2 * CH), 256, 0, stream>>>(
        out1c, WihF, WihB, bihF, bihB, gi, flag, c, 1, CH);
    rec_kernel<<<8, 512, 0, stream>>>(
        gi, WhhF, WhhB, bhhF, bhhB,
        hstate + (size_t)2 * B_ * H_, nullptr, d_out, flag, c, 1, CH);
  }

  h_epi<<<256, 256, 0, stream>>>(d_out, flag);
}

// Round 6
// 15073.888 us; speedup vs baseline: 6.5291x; 6.5291x over previous
//
#include <hip/hip_runtime.h>

// ---------------------------------------------------------------------------
// Bidirectional stacked GRU decoder. B=64, S=512, I=H=512, L=2. All device
// buffers f32 (confirmed). Internal: bf16 MFMA operands, f32 h master.
//
// Round-6 = round-4 design, compile-fixed (arg list) + hardened grid sync
// (all-thread release/acquire agent fences around the flag barrier).
//
// Weight-stationary recurrence:
//   rec grid = 64 WGs = dir(2) x col-slice(32). Each WG owns 16 output cols:
//   Whh slice [3][16][512] bf16 in LDS (filled once, inline f32->bf16), h
//   master f32 slice [64][16] in LDS. Per step: read full h (bf16, global
//   double buffer, 64KB from L2), 192 MFMA, fused gate epilogue, write own
//   h_new slice, per-dir flag sync.
//   gi: bf16, transposed layout [d][t][g(1536)][b(64)] -> 8B vector access
//   on both producer and consumer side.
// ---------------------------------------------------------------------------

#define B_ 64
#define S_ 512
#define H_ 512
#define G3_ 1536

typedef __attribute__((ext_vector_type(8))) __bf16 bf16x8;
typedef __attribute__((ext_vector_type(8))) short short8;
typedef __attribute__((ext_vector_type(4))) unsigned short us4;
typedef __attribute__((ext_vector_type(4))) float f32x4;

__device__ __forceinline__ float b2f(unsigned short u) {
  union { unsigned int i; float f; } v; v.i = ((unsigned int)u) << 16; return v.f;
}
__device__ __forceinline__ unsigned short f2b(float f) {
  union { float f; unsigned int i; } v; v.f = f;
  unsigned int x = v.i;
  return (unsigned short)((x + 0x7fffu + ((x >> 16) & 1u)) >> 16);
}
__device__ __forceinline__ bf16x8 load8(const unsigned short* p) {
  short8 s = *(const short8*)p;
  return __builtin_bit_cast(bf16x8, s);
}
__device__ __forceinline__ bf16x8 load8f(const float* p) {
  f32x4 a = *(const f32x4*)p, b = *(const f32x4*)(p + 4);
  short8 s;
  s[0] = (short)f2b(a[0]); s[1] = (short)f2b(a[1]);
  s[2] = (short)f2b(a[2]); s[3] = (short)f2b(a[3]);
  s[4] = (short)f2b(b[0]); s[5] = (short)f2b(b[1]);
  s[6] = (short)f2b(b[2]); s[7] = (short)f2b(b[3]);
  return __builtin_bit_cast(bf16x8, s);
}
__device__ __forceinline__ f32x4 mfma16(bf16x8 a, bf16x8 b, f32x4 c) {
  return __builtin_amdgcn_mfma_f32_16x16x32_bf16(a, b, c, 0, 0, 0);
}
// Overflow-proof activations (exp sees only non-positive args).
__device__ __forceinline__ float sigmoidf_(float x) {
  float e = __expf(-fabsf(x));
  float s = e / (1.0f + e);
  return x >= 0.0f ? 1.0f - s : s;
}
__device__ __forceinline__ float tanhf_(float x) {
  float e = __expf(-2.0f * fabsf(x));
  float r = (1.0f - e) / (1.0f + e);
  return x >= 0.0f ? r : -r;
}

// ---------------------------------------------------------------------------
__global__ void cvt_k(const float* __restrict__ in, unsigned short* __restrict__ out, int n) {
  int i = (blockIdx.x * 256 + threadIdx.x) * 4;
  if (i >= n) return;
  f32x4 v = *(const f32x4*)(in + i);
  us4 o;
  o[0] = f2b(v[0]); o[1] = f2b(v[1]); o[2] = f2b(v[2]); o[3] = f2b(v[3]);
  *(us4*)(out + i) = o;
}

// ---------------------------------------------------------------------------
// init: hstate f32 [layer][dir][b][H] (both layers start from the SAME
// encoder slice — the reference passes h0 to every layer's scan) + hbuf bf16
// parity-0 copies. hbuf layout: [(layer*2+dir)*2 + parity][b][H] bf16
// ---------------------------------------------------------------------------
__global__ void init_state(const float* __restrict__ enc,
                           float* __restrict__ hstate,
                           unsigned short* __restrict__ hbuf) {
  int i = blockIdx.x * 256 + threadIdx.x;      // 0 .. 65535
  if (i >= B_ * 2 * H_) return;
  int b = i >> 10, j = i & 1023;
  int d = j >> 9, c = j & 511;
  float v = enc[i];
  unsigned short vb = f2b(v);
#pragma unroll
  for (int l = 0; l < 2; ++l) {
    hstate[(((size_t)l * 2 + d) * B_ + b) * H_ + c] = v;
    hbuf[(((size_t)(l * 2 + d) * 2) * B_ + b) * H_ + c] = vb;
  }
}

// ---------------------------------------------------------------------------
// gi GEMM: gi_t[d][tmd][g][b] = A[b,t(d,tmd)] . Wih[g] + bih[g]  (bf16 out).
// Grid (24, 2*CH), block 256 (4 waves). Wave strip: 16 batches x 64 g-cols.
// ---------------------------------------------------------------------------
__global__ __launch_bounds__(256) void gi_gemm(
    const float* __restrict__ x,               // layer-0 input (f32) [B][S][H]
    const unsigned short* __restrict__ out1c,  // layer-1 input (bf16) [d][n][b][H]
    const void* __restrict__ WihF, const void* __restrict__ WihB, int wbf,
    const float* __restrict__ bihF, const float* __restrict__ bihB,
    unsigned short* __restrict__ gi_t,         // [2][CH][G3][64] bf16
    int chunk, int layer, int CH) {
  const int lane = threadIdx.x & 63;
  const int wv = threadIdx.x >> 6;             // 0..3
  const int tn = blockIdx.x;                   // 0..23
  const int tm = blockIdx.y;                   // 0..2CH-1
  const int d = (tm >= CH) ? 1 : 0;
  const int tmd = tm - d * CH;
  const int rowA = lane & 15;
  const int kb = lane >> 4;
  const int bb = wv * 16 + rowA;               // batch row loaded for A

  // A fragments, K=512
  bf16x8 afr[16];
  if (layer == 0) {
    int tt = chunk * CH + tmd;
    int t = d ? (S_ - 1 - tt) : tt;
    const float* ap = x + ((size_t)bb * S_ + t) * H_ + kb * 8;
#pragma unroll
    for (int kk = 0; kk < 16; ++kk) afr[kk] = load8f(ap + kk * 32);
  } else {
    const unsigned short* ap = out1c + ((size_t)(d * CH + tmd) * B_ + bb) * H_ + kb * 8;
#pragma unroll
    for (int kk = 0; kk < 16; ++kk) afr[kk] = load8(ap + kk * 32);
  }

  const size_t WOFF = (size_t)layer * G3_ * H_;
  const float* bih = (d ? bihB : bihF) + layer * G3_;
  f32x4 acc[4] = {{0,0,0,0},{0,0,0,0},{0,0,0,0},{0,0,0,0}};

  if (wbf) {
    const unsigned short* W = (const unsigned short*)(d ? WihB : WihF);
#pragma unroll 2
    for (int kk = 0; kk < 16; ++kk) {
#pragma unroll
      for (int nt = 0; nt < 4; ++nt) {
        bf16x8 b = load8(W + WOFF + (size_t)(tn * 64 + nt * 16 + rowA) * H_ + kb * 8 + kk * 32);
        acc[nt] = mfma16(afr[kk], b, acc[nt]);
      }
    }
  } else {
    const float* W = (const float*)(d ? WihB : WihF);
#pragma unroll 2
    for (int kk = 0; kk < 16; ++kk) {
#pragma unroll
      for (int nt = 0; nt < 4; ++nt) {
        bf16x8 b = load8f(W + WOFF + (size_t)(tn * 64 + nt * 16 + rowA) * H_ + kb * 8 + kk * 32);
        acc[nt] = mfma16(afr[kk], b, acc[nt]);
      }
    }
  }

  // C: col g = tn*64+nt*16+rowA, row (batch) = wv*16 + kb*4 + rg
#pragma unroll
  for (int nt = 0; nt < 4; ++nt) {
    int g = tn * 64 + nt * 16 + rowA;
    float bbi = bih[g];
    us4 o;
#pragma unroll
    for (int rg = 0; rg < 4; ++rg) o[rg] = f2b(acc[nt][rg] + bbi);
    *(us4*)(gi_t + ((size_t)(d * CH + tmd) * G3_ + g) * 64 + wv * 16 + kb * 4) = o;
  }
}

// ---------------------------------------------------------------------------
// Weight-stationary recurrence. Grid 64 = dir(2) x col-slice(32), block 256.
// ---------------------------------------------------------------------------
__global__ __launch_bounds__(256) void rec_kernel(
    const unsigned short* __restrict__ gi_t,   // [2][CH][G3][64] bf16
    const float* __restrict__ WhhF, const float* __restrict__ WhhB,
    const float* __restrict__ bhhF, const float* __restrict__ bhhB,
    float* __restrict__ hstate,                // [layer][dir][b][H] f32 (base)
    unsigned short* __restrict__ hbuf,         // [(layer*2+d)*2+p][b][H] bf16 (base)
    unsigned short* __restrict__ out1c,        // layer-0 dest [d][n][b][H] bf16
    float* __restrict__ dout,                  // layer-1 dest [B][S][2H] f32
    int* __restrict__ cnt,                     // [dir][1024]
    int chunk, int layer, int CH, int NCH) {
  __shared__ __align__(16) unsigned short wsl[48 * 520];  // [g*16+c][512 pad 520]
  __shared__ float hfl[64 * 17];                          // h master f32 slice

  const int tid = threadIdx.x;
  const int lane = tid & 63;
  const int wv = tid >> 6;                     // 0..3
  const int d = (int)blockIdx.x >> 5;
  const int cb = (int)blockIdx.x & 31;
  const int colbase = cb * 16;
  const int rowA = lane & 15;
  const int kb = lane >> 4;

  const float* Whh = d ? WhhB : WhhF;
  const float* bhh = (d ? bhhB : bhhF) + layer * G3_;
  const size_t WOFF = (size_t)layer * G3_ * H_;

  // One-time LDS fill: Whh slice (rows g*512+colbase+c), inline f32->bf16.
  for (int i = tid; i < 48 * 64; i += 256) {
    int r = i >> 6, j8 = (i & 63) * 8;         // r = g*16+c
    int g = r >> 4, c = r & 15;
    const float* f = Whh + WOFF + (size_t)(g * 512 + colbase + c) * H_ + j8;
    bf16x8 v = load8f(f);
    *(short8*)&wsl[r * 520 + j8] = __builtin_bit_cast(short8, v);
  }
  // h master f32 slice
  const size_t HOFF = ((size_t)layer * 2 + d) * B_ * H_;
  for (int i = tid; i < 64 * 16; i += 256) {
    int b = i >> 4, c = i & 15;
    hfl[b * 17 + c] = hstate[HOFF + (size_t)b * H_ + colbase + c];
  }
  __syncthreads();

  const int col16 = rowA;
  const int hc = colbase + col16;
  const float bhr = bhh[hc], bhz = bhh[512 + hc], bhn = bhh[1024 + hc];
  unsigned short* hb_base = hbuf + (size_t)((layer * 2 + d) * 2) * B_ * H_;
  const int bq = wv * 16 + kb * 4;             // C rows (batches) this lane owns

  for (int n = 0; n < CH; ++n) {
    const int p = n & 1;                       // global parity: chunk*CH even
    const unsigned short* hb_cur = hb_base + (size_t)p * B_ * H_;
    unsigned short* hb_nxt = hb_base + (size_t)(p ^ 1) * B_ * H_;

    // A fragments: full h (64 rows via 4 waves x 16), K=512
    bf16x8 afr[16];
#pragma unroll
    for (int kk = 0; kk < 16; ++kk)
      afr[kk] = load8(hb_cur + (size_t)(wv * 16 + rowA) * H_ + kk * 32 + kb * 8);

    f32x4 ar = {0,0,0,0}, az = {0,0,0,0}, an = {0,0,0,0};
#pragma unroll
    for (int kk = 0; kk < 16; ++kk) {
      bf16x8 br = load8(&wsl[(col16) * 520 + kk * 32 + kb * 8]);
      bf16x8 bz = load8(&wsl[(16 + col16) * 520 + kk * 32 + kb * 8]);
      bf16x8 bn = load8(&wsl[(32 + col16) * 520 + kk * 32 + kb * 8]);
      ar = mfma16(afr[kk], br, ar);
      az = mfma16(afr[kk], bz, az);
      an = mfma16(afr[kk], bn, an);
    }

    // gi: 3 gates x 4 own batches, 8B vector loads
    const size_t gib = (size_t)(d * CH + n) * G3_ * 64;
    us4 g0 = *(const us4*)(gi_t + gib + (size_t)hc * 64 + bq);
    us4 g1 = *(const us4*)(gi_t + gib + (size_t)(512 + hc) * 64 + bq);
    us4 g2 = *(const us4*)(gi_t + gib + (size_t)(1024 + hc) * 64 + bq);

    const int t_l = chunk * CH + n;
#pragma unroll
    for (int rg = 0; rg < 4; ++rg) {
      int b = bq + rg;
      float hprev = hfl[b * 17 + col16];
      float r = sigmoidf_(b2f(g0[rg]) + ar[rg] + bhr);
      float z = sigmoidf_(b2f(g1[rg]) + az[rg] + bhz);
      float nn = tanhf_(b2f(g2[rg]) + r * (an[rg] + bhn));
      float hnew = (1.0f - z) * nn + z * hprev;
      hfl[b * 17 + col16] = hnew;
      unsigned short hb16 = f2b(hnew);
      hb_nxt[(size_t)b * H_ + hc] = hb16;
      if (layer == 0) {
        out1c[((size_t)(d * CH + n) * B_ + b) * H_ + hc] = hb16;
      } else {
        int t = d ? (S_ - 1 - t_l) : t_l;
        dout[((size_t)b * S_ + t) * (2 * H_) + (size_t)d * H_ + hc] = hnew;
      }
    }

    // per-dir grid barrier: publish(all threads) -> arrive/spin -> invalidate
    __builtin_amdgcn_fence(__ATOMIC_RELEASE, "agent");   // publish own stores
    __syncthreads();
    if (tid == 0) {
      int gstep = (layer * NCH + chunk) * CH + n;        // < 1024
      int* cp = cnt + d * 1024 + gstep;
      __hip_atomic_fetch_add(cp, 1, __ATOMIC_RELAXED, __HIP_MEMORY_SCOPE_AGENT);
      while (__hip_atomic_load(cp, __ATOMIC_RELAXED, __HIP_MEMORY_SCOPE_AGENT) < 32)
        __builtin_amdgcn_s_sleep(2);
    }
    __syncthreads();
    __builtin_amdgcn_fence(__ATOMIC_ACQUIRE, "agent");   // see others' stores
  }

  // persist h master
  for (int i = tid; i < 64 * 16; i += 256) {
    int b = i >> 4, c = i & 15;
    hstate[HOFF + (size_t)b * H_ + colbase + c] = hfl[b * 17 + c];
  }
}

// ---------------------------------------------------------------------------
// Final hidden epilogue: h_f = out[:, S-1, :H], h_b = out[:, 0, H:2H]
// ---------------------------------------------------------------------------
__global__ void h_epi(float* __restrict__ dout) {
  int i = blockIdx.x * 256 + threadIdx.x;      // 0 .. 65535
  if (i >= B_ * 2 * H_) return;
  int b = i >> 10, j = i & 1023;
  int t = (j < H_) ? (S_ - 1) : 0;
  dout[(size_t)B_ * S_ * 2 * H_ + i] = dout[((size_t)b * S_ + t) * (2 * H_) + j];
}

// ---------------------------------------------------------------------------
extern "C" void kernel_launch(void* const* d_in, const int* in_sizes, int n_in,
                              void* d_out, int out_size, void* d_ws, size_t ws_size,
                              hipStream_t stream) {
  const float* x    = (const float*)d_in[0];
  const float* enc  = (const float*)d_in[1];
  const float* WihF = (const float*)d_in[2];
  const float* WhhF = (const float*)d_in[3];
  const float* bihF = (const float*)d_in[4];
  const float* bhhF = (const float*)d_in[5];
  const float* WihB = (const float*)d_in[6];
  const float* WhhB = (const float*)d_in[7];
  const float* bihB = (const float*)d_in[8];
  const float* bhhB = (const float*)d_in[9];
  float* out = (float*)d_out;

  // ws: [cnt 8K][hstate 1M][hbuf 1M][gi_t CH*384K][out1c CH*128K][WihC 6M opt]
  char* ws = (char*)d_ws;
  int* cnt      = (int*)ws;                                  // 8,192 B
  float* hstate = (float*)(ws + 8192);                       // 1,048,576 B
  unsigned short* hbuf = (unsigned short*)(ws + 8192 + 1048576);  // 1,048,576 B
  size_t off = 8192 + 1048576 + 1048576;
  int CH = 32;
  while (CH > 2 && off + (size_t)CH * 524288 > ws_size) CH >>= 1;
  unsigned short* gi_t  = (unsigned short*)(ws + off);       // CH*393,216 B
  unsigned short* out1c = (unsigned short*)(ws + off + (size_t)CH * 393216);
  size_t off2 = off + (size_t)CH * 524288;
  const int wbf = (off2 + 6291456 <= ws_size) ? 1 : 0;
  unsigned short* WihFc = (unsigned short*)(ws + off2);
  unsigned short* WihBc = WihFc + 1572864;
  const int NCH = S_ / CH;

  (void)hipMemsetAsync(cnt, 0, 8192, stream);
  if (wbf) {
    cvt_k<<<1536, 256, 0, stream>>>(WihF, WihFc, 2 * G3_ * H_);
    cvt_k<<<1536, 256, 0, stream>>>(WihB, WihBc, 2 * G3_ * H_);
  }
  init_state<<<256, 256, 0, stream>>>(enc, hstate, hbuf);

  for (int c = 0; c < NCH; ++c) {
    gi_gemm<<<dim3(24, 2 * CH), 256, 0, stream>>>(
        x, out1c,
        wbf ? (const void*)WihFc : (const void*)WihF,
        wbf ? (const void*)WihBc : (const void*)WihB, wbf,
        bihF, bihB, gi_t, c, 0, CH);
    rec_kernel<<<64, 256, 0, stream>>>(
        gi_t, WhhF, WhhB, bhhF, bhhB, hstate, hbuf, out1c, out, cnt, c, 0, CH, NCH);
    gi_gemm<<<dim3(24, 2 * CH), 256, 0, stream>>>(
        x, out1c,
        wbf ? (const void*)WihFc : (const void*)WihF,
        wbf ? (const void*)WihBc : (const void*)WihB, wbf,
        bihF, bihB, gi_t, c, 1, CH);
    rec_kernel<<<64, 256, 0, stream>>>(
        gi_t, WhhF, WhhB, bhhF, bhhB, hstate, hbuf, out1c, out, cnt, c, 1, CH, NCH);
  }

  h_epi<<<256, 256, 0, stream>>>(out);
}

// Round 7
// 5114.989 us; speedup vs baseline: 19.2413x; 2.9470x over previous
//
#include <hip/hip_runtime.h>

// ---------------------------------------------------------------------------
// Bidirectional stacked GRU decoder. B=64, S=512, I=H=512, L=2. f32 I/O.
//
// Round-7: single persistent fused kernel.
//   Grid 128 WGs = layer(2) x dir(2) x col-slice(32), 256 thr (4 waves), 1 WG/CU
//   (102KB LDS). Each WG: Wih & Whh 16-col slices in LDS (bf16, loaded once),
//   h-master f32 slice in LDS. Per step t:
//     gates = x_t·Wih (layer0; x read direct, f32->bf16 inline)  or
//             h0_t·Wih (layer1, from layer-0's ring)  +  h_{t-1}·Whh (own ring)
//     r/z share one MFMA accumulator chain (bias-folded); n keeps i/h split.
//   h exchange: depth-4 global ring of bf16 [64][512] slots, written/read with
//   agent-scope relaxed 8B atomics (coherent, no per-step L2 wb/inv fences);
//   per-(layer,dir,t) arrival flags; vmcnt-drain before flag add. Layer-1 lags
//   layer-0 by 1 step -> 512-step critical path.
// ---------------------------------------------------------------------------

#define B_ 64
#define S_ 512
#define H_ 512
#define G3_ 1536

typedef __attribute__((ext_vector_type(8))) __bf16 bf16x8;
typedef __attribute__((ext_vector_type(8))) short short8;
typedef __attribute__((ext_vector_type(2))) unsigned long long ull2;
typedef __attribute__((ext_vector_type(4))) float f32x4;
typedef unsigned long long ull;

__device__ __forceinline__ float b2f(unsigned short u) {
  union { unsigned int i; float f; } v; v.i = ((unsigned int)u) << 16; return v.f;
}
__device__ __forceinline__ unsigned short f2b(float f) {
  union { float f; unsigned int i; } v; v.f = f;
  unsigned int x = v.i;
  return (unsigned short)((x + 0x7fffu + ((x >> 16) & 1u)) >> 16);
}
__device__ __forceinline__ bf16x8 load8(const unsigned short* p) {
  short8 s = *(const short8*)p;
  return __builtin_bit_cast(bf16x8, s);
}
__device__ __forceinline__ bf16x8 load8f(const float* p) {
  f32x4 a = *(const f32x4*)p, b = *(const f32x4*)(p + 4);
  short8 s;
  s[0] = (short)f2b(a[0]); s[1] = (short)f2b(a[1]);
  s[2] = (short)f2b(a[2]); s[3] = (short)f2b(a[3]);
  s[4] = (short)f2b(b[0]); s[5] = (short)f2b(b[1]);
  s[6] = (short)f2b(b[2]); s[7] = (short)f2b(b[3]);
  return __builtin_bit_cast(bf16x8, s);
}
__device__ __forceinline__ f32x4 mfma16(bf16x8 a, bf16x8 b, f32x4 c) {
  return __builtin_amdgcn_mfma_f32_16x16x32_bf16(a, b, c, 0, 0, 0);
}
__device__ __forceinline__ float sigmoidf_(float x) {
  float e = __expf(-fabsf(x));
  float s = e / (1.0f + e);
  return x >= 0.0f ? 1.0f - s : s;
}
__device__ __forceinline__ float tanhf_(float x) {
  float e = __expf(-2.0f * fabsf(x));
  float r = (1.0f - e) / (1.0f + e);
  return x >= 0.0f ? r : -r;
}
// agent-scope coherent 16B (2x8B) ring read -> bf16x8
__device__ __forceinline__ bf16x8 load16a(ull* p) {
  ull2 v;
  v[0] = __hip_atomic_load(p, __ATOMIC_RELAXED, __HIP_MEMORY_SCOPE_AGENT);
  v[1] = __hip_atomic_load(p + 1, __ATOMIC_RELAXED, __HIP_MEMORY_SCOPE_AGENT);
  return __builtin_bit_cast(bf16x8, v);
}
__device__ __forceinline__ void spin_ge32(int* p) {
  while (__hip_atomic_load(p, __ATOMIC_RELAXED, __HIP_MEMORY_SCOPE_AGENT) < 32)
    __builtin_amdgcn_s_sleep(2);
}

// ---------------------------------------------------------------------------
// init ring slot 3 (the "h before step 0") for all (layer,dir) from enc.
// ring layout (ull units): [(l*2+d)][slot(4)][8192]  (slot = [b(64)][512] bf16)
// ---------------------------------------------------------------------------
__global__ void init_ring(const float* __restrict__ enc, ull* __restrict__ ring) {
  int i = blockIdx.x * 256 + threadIdx.x;      // 0..32767
  if (i >= 32768) return;
  int ld = i >> 13;                            // (l*2+d)
  int d = ld & 1;
  int u = i & 8191;                            // ull index within slot
  int e4 = u * 4;
  int b = e4 >> 9, c = e4 & 511;
  const float* e = enc + b * 1024 + d * 512 + c;
  ull v = 0;
#pragma unroll
  for (int j = 0; j < 4; ++j) v |= (ull)f2b(e[j]) << (16 * j);
  ring[(size_t)ld * 32768 + 3 * 8192 + u] = v;
}

// ---------------------------------------------------------------------------
// Persistent fused GRU. Grid 128 = l(2) x d(2) x cb(32), block 256.
// ---------------------------------------------------------------------------
__global__ __launch_bounds__(256) void gru_fused(
    const float* __restrict__ x,               // [B][S][H] f32
    const float* __restrict__ enc,             // [B][2H] f32
    const float* __restrict__ WihF, const float* __restrict__ WihB,
    const float* __restrict__ WhhF, const float* __restrict__ WhhB,
    const float* __restrict__ bihF, const float* __restrict__ bihB,
    const float* __restrict__ bhhF, const float* __restrict__ bhhB,
    ull* __restrict__ ring,                    // [(l*2+d)][4][8192] ull
    int* __restrict__ flags,                   // [(l*2+d)][512]
    float* __restrict__ dout) {                // [B][S][2H] f32
  __shared__ __align__(16) unsigned short wih[48 * 520];
  __shared__ __align__(16) unsigned short whh[48 * 520];
  __shared__ float hfl[64 * 17];

  const int tid = threadIdx.x;
  const int lane = tid & 63;
  const int wv = tid >> 6;                     // 0..3
  const int wg = (int)blockIdx.x;
  const int l = wg >> 6, d = (wg >> 5) & 1, cb = wg & 31;
  const int colbase = cb * 16;
  const int rowA = lane & 15, kb = lane >> 4;

  const float* Wih = (d ? WihB : WihF) + (size_t)l * G3_ * H_;
  const float* Whh = (d ? WhhB : WhhF) + (size_t)l * G3_ * H_;
  const float* bi = (d ? bihB : bihF) + l * G3_;
  const float* bh = (d ? bhhB : bhhF) + l * G3_;

  // one-time LDS fill: 16-col slices of Wih/Whh (rows g*512+colbase+c), bf16
  for (int i = tid; i < 48 * 64; i += 256) {
    int r = i >> 6, j8 = (i & 63) * 8;         // r = g*16+c
    int g = r >> 4, c = r & 15;
    size_t gro = (size_t)(g * 512 + colbase + c) * H_ + j8;
    *(short8*)&wih[r * 520 + j8] = __builtin_bit_cast(short8, load8f(Wih + gro));
    *(short8*)&whh[r * 520 + j8] = __builtin_bit_cast(short8, load8f(Whh + gro));
  }
  // h master f32 slice from enc (every layer starts from h0 — reference quirk)
  for (int i = tid; i < 64 * 16; i += 256) {
    int b = i >> 4, c = i & 15;
    hfl[b * 17 + c] = enc[b * 1024 + d * 512 + colbase + c];
  }
  __syncthreads();

  const int col16 = rowA;
  const int hc = colbase + col16;
  const float brz_r = bi[hc] + bh[hc];
  const float brz_z = bi[512 + hc] + bh[512 + hc];
  const float bi_n = bi[1024 + hc];
  const float bh_n = bh[1024 + hc];

  int* f0 = flags + d * 512;                   // layer-0, this dir
  int* f1 = flags + (2 + d) * 512;             // layer-1, this dir
  int* fown = flags + (l * 2 + d) * 512;
  ull* ring0 = ring + (size_t)d * 32768;
  ull* ringl = ring + (size_t)(l * 2 + d) * 32768;
  const int bq = wv * 16 + kb * 4;             // C rows (batches) this lane owns
  const int arow = wv * 16 + rowA;             // A row this lane loads

  for (int t = 0; t < 512; ++t) {
    // x A-frags (layer 0): flag-independent — issue before the spin
    bf16x8 aIn[16];
    if (l == 0) {
      int txx = d ? (511 - t) : t;
      const float* ap = x + ((size_t)arow * 512 + txx) * 512 + kb * 8;
#pragma unroll
      for (int kk = 0; kk < 16; ++kk) aIn[kk] = load8f(ap + kk * 32);
    }

    // waits: l0: own prev step + ring-slot free (consumer l1 at t-4);
    //        l1: producer at t + own prev step.
    if (tid == 0) {
      if (l == 0) {
        if (t > 0) spin_ge32(f0 + t - 1);
        if (t >= 4) spin_ge32(f1 + t - 4);
      } else {
        spin_ge32(f0 + t);
        if (t > 0) spin_ge32(f1 + t - 1);
      }
    }
    __syncthreads();

    if (l == 1) {                              // layer-0 output at step t
      ull* rp = ring0 + (size_t)(t & 3) * 8192;
#pragma unroll
      for (int kk = 0; kk < 16; ++kk) {
        int eb = arow * 512 + kk * 32 + kb * 8;
        aIn[kk] = load16a(rp + (eb >> 2));
      }
    }
    ull* rpo = ringl + (size_t)((t + 3) & 3) * 8192;   // own h_{t-1}
    bf16x8 aOwn[16];
#pragma unroll
    for (int kk = 0; kk < 16; ++kk) {
      int eb = arow * 512 + kk * 32 + kb * 8;
      aOwn[kk] = load16a(rpo + (eb >> 2));
    }

    f32x4 accr = {0,0,0,0}, accz = {0,0,0,0}, acni = {0,0,0,0}, acnh = {0,0,0,0};
#pragma unroll
    for (int kk = 0; kk < 16; ++kk) {
      const int o = kk * 32 + kb * 8;
      accr = mfma16(aIn[kk],  load8(&wih[col16 * 520 + o]), accr);
      accr = mfma16(aOwn[kk], load8(&whh[col16 * 520 + o]), accr);
      accz = mfma16(aIn[kk],  load8(&wih[(16 + col16) * 520 + o]), accz);
      accz = mfma16(aOwn[kk], load8(&whh[(16 + col16) * 520 + o]), accz);
      acni = mfma16(aIn[kk],  load8(&wih[(32 + col16) * 520 + o]), acni);
      acnh = mfma16(aOwn[kk], load8(&whh[(32 + col16) * 520 + o]), acnh);
    }

    const int tox = d ? (511 - t) : t;
#pragma unroll
    for (int rg = 0; rg < 4; ++rg) {
      int b = bq + rg;
      float hprev = hfl[b * 17 + col16];
      float r = sigmoidf_(accr[rg] + brz_r);
      float z = sigmoidf_(accz[rg] + brz_z);
      float n = tanhf_(acni[rg] + bi_n + r * (acnh[rg] + bh_n));
      float hnew = (1.0f - z) * n + z * hprev;
      hfl[b * 17 + col16] = hnew;
      if (l == 1)
        dout[((size_t)b * 512 + tox) * 1024 + d * 512 + hc] = hnew;
    }
    __syncthreads();                           // hfl slice complete

    // publish own 16-col slice to ring slot t&3 (coherent 8B stores)
    {
      int b = tid >> 2, q = tid & 3;
      ull v = 0;
#pragma unroll
      for (int j = 0; j < 4; ++j)
        v |= (ull)f2b(hfl[b * 17 + q * 4 + j]) << (16 * j);
      __hip_atomic_store(ringl + (size_t)(t & 3) * 8192 +
                             ((b * 512 + colbase + q * 4) >> 2),
                         v, __ATOMIC_RELAXED, __HIP_MEMORY_SCOPE_AGENT);
    }
    asm volatile("s_waitcnt vmcnt(0)" ::: "memory");   // stores at coherence pt
    if (tid == 0)
      __hip_atomic_fetch_add(fown + t, 1, __ATOMIC_RELAXED,
                             __HIP_MEMORY_SCOPE_AGENT);
  }
}

// ---------------------------------------------------------------------------
// Final hidden epilogue: h_f = out[:, S-1, :H], h_b = out[:, 0, H:2H]
// ---------------------------------------------------------------------------
__global__ void h_epi(float* __restrict__ dout) {
  int i = blockIdx.x * 256 + threadIdx.x;      // 0 .. 65535
  if (i >= B_ * 2 * H_) return;
  int b = i >> 10, j = i & 1023;
  int t = (j < H_) ? (S_ - 1) : 0;
  dout[(size_t)B_ * S_ * 2 * H_ + i] = dout[((size_t)b * S_ + t) * (2 * H_) + j];
}

// ---------------------------------------------------------------------------
extern "C" void kernel_launch(void* const* d_in, const int* in_sizes, int n_in,
                              void* d_out, int out_size, void* d_ws, size_t ws_size,
                              hipStream_t stream) {
  const float* x    = (const float*)d_in[0];
  const float* enc  = (const float*)d_in[1];
  const float* WihF = (const float*)d_in[2];
  const float* WhhF = (const float*)d_in[3];
  const float* bihF = (const float*)d_in[4];
  const float* bhhF = (const float*)d_in[5];
  const float* WihB = (const float*)d_in[6];
  const float* WhhB = (const float*)d_in[7];
  const float* bihB = (const float*)d_in[8];
  const float* bhhB = (const float*)d_in[9];
  float* out = (float*)d_out;

  // ws: [flags 8KB][ring 1MB]
  char* ws = (char*)d_ws;
  int* flags = (int*)ws;
  ull* ring  = (ull*)(ws + 8192);

  (void)hipMemsetAsync(flags, 0, 8192, stream);
  init_ring<<<128, 256, 0, stream>>>(enc, ring);
  gru_fused<<<128, 256, 0, stream>>>(x, enc, WihF, WihB, WhhF, WhhB,
                                     bihF, bihB, bhhF, bhhB,
                                     ring, flags, out);
  h_epi<<<256, 256, 0, stream>>>(out);
}